// Round 11
// baseline (381.853 us; speedup 1.0000x reference)
//
#include <hip/hip_runtime.h>

#define N_NODES 50000
#define N_EDGES 1600000
#define ETOT (N_EDGES + N_NODES)   // 1,650,000 (self-loops appended)
#define F_IN 2304
#define HD 64    // H1*D1
#define H1 8
#define D1 8
#define NC 5
#define KB (F_IN / 32)                    // 72 K-blocks
#define NTILE (N_NODES / 16)              // 3125 wave tiles
#define GEMM_BLOCKS ((NTILE + 3) / 4)     // 782
#define HIST_BLOCKS 2048
#define PACKW_THREADS (KB * 4 * 64)       // 18432
#define SCAN_PER_THREAD 49                // 49*1024 >= 50000

typedef __attribute__((ext_vector_type(8))) short short8v;
typedef __attribute__((ext_vector_type(4))) float f32x4;

__device__ __forceinline__ float lrelu(float x) { return x > 0.f ? x : 0.2f * x; }

__device__ __forceinline__ unsigned short f2bf(float f) {   // RNE fp32->bf16
    unsigned u = __float_as_uint(f);
    u += 0x7fffu + ((u >> 16) & 1u);
    return (unsigned short)(u >> 16);
}
__device__ __forceinline__ float bf2f(unsigned short u) {
    return __uint_as_float(((unsigned)u) << 16);
}

__device__ __forceinline__ void edge_sd(const int* __restrict__ ei, int e, int& s, int& t) {
    if (e < N_EDGES) { s = ei[e]; t = ei[N_EDGES + e]; }
    else { s = e - N_EDGES; t = s; }
}

// ============ W1 pre-pack into MFMA B-fragment layout (bf16) + deg zeroing ============
__global__ void packW_kernel(const float* __restrict__ W, short* __restrict__ Wp,
                             unsigned* __restrict__ deg) {
    int idx = blockIdx.x * 256 + threadIdx.x;   // (k0*4+cb)*64+lane
    // fold deg zero-init into this launch (grid-stride)
    for (int i = idx; i < N_NODES; i += PACKW_THREADS) deg[i] = 0u;
    if (idx >= PACKW_THREADS) return;
    int lane = idx & 63;
    int cb = (idx >> 6) & 3;
    int k0 = idx >> 8;
    int colg = cb * 16 + (lane & 15);
    int kbase = k0 * 32 + (lane >> 4) * 8;
    short8v v;
    #pragma unroll
    for (int j = 0; j < 8; j++)
        v[j] = (short)f2bf(W[(kbase + j) * HD + colg]);
    *reinterpret_cast<short8v*>(&Wp[(long)idx * 8]) = v;
}

// ==== FAT kernel: gemm1 (MFMA + fused layer-1 attention terms)  ||  hist ====
// gemm: R8-proven 2-deep x prefetch; one wave per 16-row tile; nontemporal x
__global__ __launch_bounds__(256) void fat_gemm_hist(const float* __restrict__ x,
                                                     const short* __restrict__ Wp,
                                                     const float* __restrict__ asrc_w,
                                                     const float* __restrict__ adst_w,
                                                     unsigned short* __restrict__ hb,
                                                     float* __restrict__ a_src,
                                                     float* __restrict__ a_dst,
                                                     const int* __restrict__ ei,
                                                     unsigned* __restrict__ deg,
                                                     int* __restrict__ epos) {
    if (blockIdx.x >= GEMM_BLOCKS) {
        int b = blockIdx.x - GEMM_BLOCKS;
        for (long e = (long)b * 256 + threadIdx.x; e < ETOT; e += (long)HIST_BLOCKS * 256) {
            int s, t; edge_sd(ei, (int)e, s, t);
            epos[e] = (int)atomicAdd(&deg[t], 1u);
        }
        return;
    }
    int wave = threadIdx.x >> 6;
    int lane = threadIdx.x & 63;
    int tile = blockIdx.x * 4 + wave;
    if (tile >= NTILE) return;
    int arow = tile * 16 + (lane & 15);
    const f32x4* xp = reinterpret_cast<const f32x4*>(x + (long)arow * F_IN + (lane >> 4) * 8);
    const short8v* wp = reinterpret_cast<const short8v*>(Wp) + lane;
    f32x4 acc0 = {}, acc1 = {}, acc2 = {}, acc3 = {};
    f32x4 x0 = __builtin_nontemporal_load(xp);
    f32x4 x1 = __builtin_nontemporal_load(xp + 1);
    f32x4 y0 = __builtin_nontemporal_load(xp + 8);
    f32x4 y1 = __builtin_nontemporal_load(xp + 9);
    xp += 16;
    for (int k0 = 0; k0 < KB - 2; k0++) {
        short8v b0 = wp[0 * 64];
        short8v b1 = wp[1 * 64];
        short8v b2 = wp[2 * 64];
        short8v b3 = wp[3 * 64];
        wp += 4 * 64;
        f32x4 z0 = __builtin_nontemporal_load(xp);
        f32x4 z1 = __builtin_nontemporal_load(xp + 1);
        xp += 8;
        short8v af;
        #pragma unroll
        for (int j = 0; j < 4; j++) af[j] = (short)f2bf(x0[j]);
        #pragma unroll
        for (int j = 0; j < 4; j++) af[4 + j] = (short)f2bf(x1[j]);
        acc0 = __builtin_amdgcn_mfma_f32_16x16x32_bf16(af, b0, acc0, 0, 0, 0);
        acc1 = __builtin_amdgcn_mfma_f32_16x16x32_bf16(af, b1, acc1, 0, 0, 0);
        acc2 = __builtin_amdgcn_mfma_f32_16x16x32_bf16(af, b2, acc2, 0, 0, 0);
        acc3 = __builtin_amdgcn_mfma_f32_16x16x32_bf16(af, b3, acc3, 0, 0, 0);
        x0 = y0; x1 = y1; y0 = z0; y1 = z1;
    }
    #pragma unroll
    for (int tb = 0; tb < 2; tb++) {   // last two K-blocks
        short8v b0 = wp[0 * 64];
        short8v b1 = wp[1 * 64];
        short8v b2 = wp[2 * 64];
        short8v b3 = wp[3 * 64];
        wp += 4 * 64;
        short8v af;
        #pragma unroll
        for (int j = 0; j < 4; j++) af[j] = (short)f2bf(tb == 0 ? x0[j] : y0[j]);
        #pragma unroll
        for (int j = 0; j < 4; j++) af[4 + j] = (short)f2bf(tb == 0 ? x1[j] : y1[j]);
        acc0 = __builtin_amdgcn_mfma_f32_16x16x32_bf16(af, b0, acc0, 0, 0, 0);
        acc1 = __builtin_amdgcn_mfma_f32_16x16x32_bf16(af, b1, acc1, 0, 0, 0);
        acc2 = __builtin_amdgcn_mfma_f32_16x16x32_bf16(af, b2, acc2, 0, 0, 0);
        acc3 = __builtin_amdgcn_mfma_f32_16x16x32_bf16(af, b3, acc3, 0, 0, 0);
    }
    // C/D layout: col = cb*16 + (lane&15), row = tile*16 + (lane>>4)*4 + r
    int c0 = lane & 15;
    long rbase = (long)(tile * 16 + (lane >> 4) * 4) * HD;
    #pragma unroll
    for (int r = 0; r < 4; r++) {
        hb[rbase + r * HD + c0]      = f2bf(acc0[r]);
        hb[rbase + r * HD + 16 + c0] = f2bf(acc1[r]);
        hb[rbase + r * HD + 32 + c0] = f2bf(acc2[r]);
        hb[rbase + r * HD + 48 + c0] = f2bf(acc3[r]);
    }
    // fused attention terms
    float wsv[4], wdv[4];
    #pragma unroll
    for (int cb = 0; cb < 4; cb++) {
        wsv[cb] = asrc_w[cb * 16 + c0];
        wdv[cb] = adst_w[cb * 16 + c0];
    }
    int nbase = tile * 16 + (lane >> 4) * 4;
    #pragma unroll
    for (int r = 0; r < 4; r++) {
        float a[4] = {acc0[r], acc1[r], acc2[r], acc3[r]};
        #pragma unroll
        for (int cb = 0; cb < 4; cb++) {
            float vs = a[cb] * wsv[cb];
            float vd = a[cb] * wdv[cb];
            vs += __shfl_xor(vs, 1, 64); vd += __shfl_xor(vd, 1, 64);
            vs += __shfl_xor(vs, 2, 64); vd += __shfl_xor(vd, 2, 64);
            vs += __shfl_xor(vs, 4, 64); vd += __shfl_xor(vd, 4, 64);
            if ((c0 & 7) == 0) {
                int hh = 2 * cb + (c0 >> 3);
                a_src[(nbase + r) * 8 + hh] = vs;
                a_dst[(nbase + r) * 8 + hh] = vd;
            }
        }
    }
}

// ============ single-launch exclusive scan (1 block, 1024 threads) ============
__global__ __launch_bounds__(1024) void scan_fused_kernel(const unsigned* __restrict__ deg,
                                                          unsigned* __restrict__ rowptr) {
    __shared__ unsigned tsum[1024];
    int tid = threadIdx.x;
    int base = tid * SCAN_PER_THREAD;
    unsigned local[SCAN_PER_THREAD];
    unsigned run = 0;
    #pragma unroll
    for (int j = 0; j < SCAN_PER_THREAD; j++) {
        int i = base + j;
        unsigned v = (i < N_NODES) ? deg[i] : 0u;
        local[j] = run;            // thread-local exclusive prefix
        run += v;
    }
    tsum[tid] = run;
    __syncthreads();
    for (int off = 1; off < 1024; off <<= 1) {
        unsigned u = (tid >= off) ? tsum[tid - off] : 0u;
        __syncthreads();
        tsum[tid] += u;
        __syncthreads();
    }
    unsigned prefix = (tid == 0) ? 0u : tsum[tid - 1];
    #pragma unroll
    for (int j = 0; j < SCAN_PER_THREAD; j++) {
        int i = base + j;
        if (i < N_NODES) rowptr[i] = prefix + local[j];
    }
    if (tid == 0) rowptr[N_NODES] = ETOT;
}

// fill: atomic-free scatter using recorded slots
__global__ void fill_kernel(const int* __restrict__ ei, const unsigned* __restrict__ rowptr,
                            const int* __restrict__ epos, int* __restrict__ col) {
    int e = blockIdx.x * blockDim.x + threadIdx.x;
    if (e >= ETOT) return;
    int s, t; edge_sd(ei, e, s, t);
    col[rowptr[t] + epos[e]] = s;
}

// ---- layer-1 agg + fused layer-2 projection (+b1) + layer-2 attention terms ----
__global__ __launch_bounds__(256) void agg1_proj2_kernel(const unsigned* __restrict__ rowptr,
                                                         const int* __restrict__ col,
                                                         const float* __restrict__ a_src,
                                                         const float* __restrict__ a_dst,
                                                         const unsigned short* __restrict__ hb,
                                                         const float* __restrict__ b1,
                                                         const float* __restrict__ W2,
                                                         const float* __restrict__ asrc2_w,
                                                         const float* __restrict__ adst2_w,
                                                         float* __restrict__ h2p,
                                                         float* __restrict__ a_src2,
                                                         float* __restrict__ a_dst2) {
    int n = blockIdx.x * 4 + (threadIdx.x >> 6);
    if (n >= N_NODES) return;
    int k = threadIdx.x & 63;
    int hh = k >> 3;
    float ad = a_dst[n * 8 + hh];
    int r0 = rowptr[n], r1 = rowptr[n + 1];
    float acc = 0.f, z = 0.f;
    int e = r0;
    for (; e + 3 < r1; e += 4) {   // 4 gathers in flight (R8-proven)
        int s0 = col[e], s1 = col[e + 1], s2 = col[e + 2], s3 = col[e + 3];
        float as0 = a_src[s0 * 8 + hh];
        float as1 = a_src[s1 * 8 + hh];
        float as2 = a_src[s2 * 8 + hh];
        float as3 = a_src[s3 * 8 + hh];
        unsigned short u0 = hb[(long)s0 * 64 + k];
        unsigned short u1 = hb[(long)s1 * 64 + k];
        unsigned short u2 = hb[(long)s2 * 64 + k];
        unsigned short u3 = hb[(long)s3 * 64 + k];
        float p0 = __expf(lrelu(as0 + ad));
        float p1 = __expf(lrelu(as1 + ad));
        float p2 = __expf(lrelu(as2 + ad));
        float p3 = __expf(lrelu(as3 + ad));
        z += (p0 + p1) + (p2 + p3);
        acc += p0 * bf2f(u0) + p1 * bf2f(u1) + p2 * bf2f(u2) + p3 * bf2f(u3);
    }
    for (; e < r1; ++e) {
        int s0 = col[e];
        float p0 = __expf(lrelu(a_src[s0 * 8 + hh] + ad));
        z += p0;
        acc += p0 * bf2f(hb[(long)s0 * 64 + k]);
    }
    // fused proj2: v = out1[n][k] + b1[k]; h2 = sum_k v * W2[k][:]
    float v = acc / (z + 1e-16f) + b1[k];
    float part[NC];
    #pragma unroll
    for (int c = 0; c < NC; c++) part[c] = v * W2[k * NC + c];
    #pragma unroll
    for (int off = 32; off >= 1; off >>= 1)
        #pragma unroll
        for (int c = 0; c < NC; c++) part[c] += __shfl_xor(part[c], off, 64);
    if (k == 0) {
        float as = 0.f, ad2 = 0.f;
        #pragma unroll
        for (int c = 0; c < NC; c++) {
            as  += part[c] * asrc2_w[c];
            ad2 += part[c] * adst2_w[c];
        }
        f32x4 h0;
        h0[0] = part[0]; h0[1] = part[1]; h0[2] = part[2]; h0[3] = part[3];
        *reinterpret_cast<f32x4*>(&h2p[n * 8]) = h0;
        h2p[n * 8 + 4] = part[4];
        h2p[n * 8 + 5] = 0.f; h2p[n * 8 + 6] = 0.f; h2p[n * 8 + 7] = 0.f;
        a_src2[n] = as;
        a_dst2[n] = ad2;
    }
}

// ---------- layer-2 fused softmax+agg+bias+log_softmax (thread per node) ----------
__global__ void agg2_kernel(const unsigned* __restrict__ rowptr, const int* __restrict__ col,
                            const float* __restrict__ a_src2, const float* __restrict__ a_dst2,
                            const float* __restrict__ h2p, const float* __restrict__ b2,
                            float* __restrict__ y) {
    int n = blockIdx.x * blockDim.x + threadIdx.x;
    if (n >= N_NODES) return;
    float ad = a_dst2[n];
    int r0 = rowptr[n], r1 = rowptr[n + 1];
    float acc[NC] = {};
    float z = 0.f;
    int e = r0;
    for (; e + 3 < r1; e += 4) {   // 4 gathers in flight
        int s0 = col[e], s1 = col[e + 1], s2 = col[e + 2], s3 = col[e + 3];
        float as0 = a_src2[s0], as1 = a_src2[s1], as2 = a_src2[s2], as3 = a_src2[s3];
        f32x4 v0 = *reinterpret_cast<const f32x4*>(&h2p[s0 * 8]);
        f32x4 v1 = *reinterpret_cast<const f32x4*>(&h2p[s1 * 8]);
        f32x4 v2 = *reinterpret_cast<const f32x4*>(&h2p[s2 * 8]);
        f32x4 v3 = *reinterpret_cast<const f32x4*>(&h2p[s3 * 8]);
        float w0 = h2p[s0 * 8 + 4], w1 = h2p[s1 * 8 + 4], w2 = h2p[s2 * 8 + 4], w3 = h2p[s3 * 8 + 4];
        float p0 = __expf(lrelu(as0 + ad));
        float p1 = __expf(lrelu(as1 + ad));
        float p2 = __expf(lrelu(as2 + ad));
        float p3 = __expf(lrelu(as3 + ad));
        z += (p0 + p1) + (p2 + p3);
        #pragma unroll
        for (int c = 0; c < 4; c++)
            acc[c] += p0 * v0[c] + p1 * v1[c] + p2 * v2[c] + p3 * v3[c];
        acc[4] += p0 * w0 + p1 * w1 + p2 * w2 + p3 * w3;
    }
    for (; e < r1; ++e) {
        int s = col[e];
        float p = __expf(lrelu(a_src2[s] + ad));
        z += p;
        f32x4 v0 = *reinterpret_cast<const f32x4*>(&h2p[s * 8]);
        float v4 = h2p[s * 8 + 4];
        acc[0] += p * v0[0]; acc[1] += p * v0[1]; acc[2] += p * v0[2];
        acc[3] += p * v0[3]; acc[4] += p * v4;
    }
    float inv = 1.f / (z + 1e-16f);
    float l[NC], mx = -3.4e38f;
    #pragma unroll
    for (int c = 0; c < NC; c++) {
        l[c] = acc[c] * inv + b2[c];
        mx = fmaxf(mx, l[c]);
    }
    float ssum = 0.f;
    #pragma unroll
    for (int c = 0; c < NC; c++) ssum += __expf(l[c] - mx);
    float lse = __logf(ssum);
    #pragma unroll
    for (int c = 0; c < NC; c++) y[n * NC + c] = l[c] - mx - lse;
}

extern "C" void kernel_launch(void* const* d_in, const int* in_sizes, int n_in,
                              void* d_out, int out_size, void* d_ws, size_t ws_size,
                              hipStream_t stream) {
    const float* x        = (const float*)d_in[0];
    const int*   ei       = (const int*)d_in[1];
    const float* W1       = (const float*)d_in[2];
    const float* att_src1 = (const float*)d_in[3];
    const float* att_dst1 = (const float*)d_in[4];
    const float* b1       = (const float*)d_in[5];
    const float* W2       = (const float*)d_in[6];
    const float* att_src2 = (const float*)d_in[7];
    const float* att_dst2 = (const float*)d_in[8];
    const float* b2       = (const float*)d_in[9];
    float* y = (float*)d_out;

    // workspace layout
    unsigned short* hb = (unsigned short*)d_ws;           // N*64 bf16
    float* a_src1  = (float*)(hb + (long)N_NODES * 64);   // N*8
    float* a_dst1  = a_src1 + N_NODES * 8;                // N*8
    float* h2p     = a_dst1 + N_NODES * 8;                // N*8 (padded NC)
    float* a_src2  = h2p + (long)N_NODES * 8;             // N
    float* a_dst2  = a_src2 + N_NODES;                    // N
    unsigned* deg    = (unsigned*)(a_dst2 + N_NODES);     // N
    unsigned* rowptr = deg + N_NODES;                     // N+1
    int*      col    = (int*)(rowptr + N_NODES + 1);      // ETOT
    int*      epos   = col + ETOT;                        // ETOT
    short*    Wp     = (short*)(epos + ETOT);             // 147456 shorts

    // packW also zero-inits deg (one launch)
    packW_kernel<<<(PACKW_THREADS + 255) / 256, 256, 0, stream>>>(W1, Wp, deg);

    // gemm1 (+fused att1) || hist, one fat launch
    fat_gemm_hist<<<GEMM_BLOCKS + HIST_BLOCKS, 256, 0, stream>>>(
        x, Wp, att_src1, att_dst1, hb, a_src1, a_dst1, ei, deg, epos);

    scan_fused_kernel<<<1, 1024, 0, stream>>>(deg, rowptr);
    fill_kernel<<<(ETOT + 255) / 256, 256, 0, stream>>>(ei, rowptr, epos, col);

    agg1_proj2_kernel<<<(N_NODES + 3) / 4, 256, 0, stream>>>(rowptr, col, a_src1, a_dst1, hb,
                                                             b1, W2, att_src2, att_dst2,
                                                             h2p, a_src2, a_dst2);
    agg2_kernel<<<(N_NODES + 255) / 256, 256, 0, stream>>>(rowptr, col, a_src2, a_dst2, h2p, b2, y);
}

// Round 12
// 338.224 us; speedup vs baseline: 1.1290x; 1.1290x over previous
//
#include <hip/hip_runtime.h>

#define N_NODES 50000
#define N_EDGES 1600000
#define ETOT (N_EDGES + N_NODES)   // 1,650,000 (self-loops appended)
#define F_IN 2304
#define HD 64    // H1*D1
#define H1 8
#define D1 8
#define NC 5
#define NB_SCAN ((N_NODES + 255) / 256)   // 196
#define KB (F_IN / 32)                    // 72 K-blocks
#define NTILE (N_NODES / 16)              // 3125 wave tiles
#define GEMM_BLOCKS ((NTILE + 3) / 4)     // 782
#define HIST_BLOCKS 2048

typedef __attribute__((ext_vector_type(8))) short short8v;
typedef __attribute__((ext_vector_type(4))) float f32x4;

__device__ __forceinline__ float lrelu(float x) { return x > 0.f ? x : 0.2f * x; }

__device__ __forceinline__ unsigned short f2bf(float f) {   // RNE fp32->bf16
    unsigned u = __float_as_uint(f);
    u += 0x7fffu + ((u >> 16) & 1u);
    return (unsigned short)(u >> 16);
}
__device__ __forceinline__ float bf2f(unsigned short u) {
    return __uint_as_float(((unsigned)u) << 16);
}

__device__ __forceinline__ void edge_sd(const int* __restrict__ ei, int e, int& s, int& t) {
    if (e < N_EDGES) { s = ei[e]; t = ei[N_EDGES + e]; }
    else { s = e - N_EDGES; t = s; }
}

// ============ W1 pre-pack into MFMA B-fragment layout (bf16) ============
__global__ void packW_kernel(const float* __restrict__ W, short* __restrict__ Wp) {
    int idx = blockIdx.x * 256 + threadIdx.x;   // (k0*4+cb)*64+lane
    if (idx >= KB * 4 * 64) return;
    int lane = idx & 63;
    int cb = (idx >> 6) & 3;
    int k0 = idx >> 8;
    int colg = cb * 16 + (lane & 15);
    int kbase = k0 * 32 + (lane >> 4) * 8;
    short8v v;
    #pragma unroll
    for (int j = 0; j < 8; j++)
        v[j] = (short)f2bf(W[(kbase + j) * HD + colg]);
    *reinterpret_cast<short8v*>(&Wp[(long)idx * 8]) = v;
}

// ==== FAT kernel: gemm1 (MFMA + fused layer-1 attention terms)  ||  hist ====
// blocks [0, GEMM_BLOCKS): one wave per 16-row tile, streams x nontemporally
// blocks [GEMM_BLOCKS, +HIST_BLOCKS): grid-stride degree histogram + slot record
__global__ __launch_bounds__(256) void fat_gemm_hist(const float* __restrict__ x,
                                                     const short* __restrict__ Wp,
                                                     const float* __restrict__ asrc_w,
                                                     const float* __restrict__ adst_w,
                                                     unsigned short* __restrict__ hb,
                                                     float* __restrict__ a_src,
                                                     float* __restrict__ a_dst,
                                                     const int* __restrict__ ei,
                                                     unsigned* __restrict__ deg,
                                                     int* __restrict__ epos) {
    if (blockIdx.x >= GEMM_BLOCKS) {
        int b = blockIdx.x - GEMM_BLOCKS;
        for (long e = (long)b * 256 + threadIdx.x; e < ETOT; e += (long)HIST_BLOCKS * 256) {
            int s, t; edge_sd(ei, (int)e, s, t);
            epos[e] = (int)atomicAdd(&deg[t], 1u);
        }
        return;
    }
    int wave = threadIdx.x >> 6;
    int lane = threadIdx.x & 63;
    int tile = blockIdx.x * 4 + wave;
    if (tile >= NTILE) return;
    int arow = tile * 16 + (lane & 15);
    const f32x4* xp = reinterpret_cast<const f32x4*>(x + (long)arow * F_IN + (lane >> 4) * 8);
    const short8v* wp = reinterpret_cast<const short8v*>(Wp) + lane;
    f32x4 acc0 = {}, acc1 = {}, acc2 = {}, acc3 = {};
    f32x4 x0 = __builtin_nontemporal_load(xp);
    f32x4 x1 = __builtin_nontemporal_load(xp + 1);
    f32x4 y0 = __builtin_nontemporal_load(xp + 8);
    f32x4 y1 = __builtin_nontemporal_load(xp + 9);
    xp += 16;
    for (int k0 = 0; k0 < KB - 2; k0++) {
        short8v b0 = wp[0 * 64];
        short8v b1 = wp[1 * 64];
        short8v b2 = wp[2 * 64];
        short8v b3 = wp[3 * 64];
        wp += 4 * 64;
        f32x4 z0 = __builtin_nontemporal_load(xp);
        f32x4 z1 = __builtin_nontemporal_load(xp + 1);
        xp += 8;
        short8v af;
        #pragma unroll
        for (int j = 0; j < 4; j++) af[j] = (short)f2bf(x0[j]);
        #pragma unroll
        for (int j = 0; j < 4; j++) af[4 + j] = (short)f2bf(x1[j]);
        acc0 = __builtin_amdgcn_mfma_f32_16x16x32_bf16(af, b0, acc0, 0, 0, 0);
        acc1 = __builtin_amdgcn_mfma_f32_16x16x32_bf16(af, b1, acc1, 0, 0, 0);
        acc2 = __builtin_amdgcn_mfma_f32_16x16x32_bf16(af, b2, acc2, 0, 0, 0);
        acc3 = __builtin_amdgcn_mfma_f32_16x16x32_bf16(af, b3, acc3, 0, 0, 0);
        x0 = y0; x1 = y1; y0 = z0; y1 = z1;
    }
    #pragma unroll
    for (int tb = 0; tb < 2; tb++) {   // last two K-blocks
        short8v b0 = wp[0 * 64];
        short8v b1 = wp[1 * 64];
        short8v b2 = wp[2 * 64];
        short8v b3 = wp[3 * 64];
        wp += 4 * 64;
        short8v af;
        #pragma unroll
        for (int j = 0; j < 4; j++) af[j] = (short)f2bf(tb == 0 ? x0[j] : y0[j]);
        #pragma unroll
        for (int j = 0; j < 4; j++) af[4 + j] = (short)f2bf(tb == 0 ? x1[j] : y1[j]);
        acc0 = __builtin_amdgcn_mfma_f32_16x16x32_bf16(af, b0, acc0, 0, 0, 0);
        acc1 = __builtin_amdgcn_mfma_f32_16x16x32_bf16(af, b1, acc1, 0, 0, 0);
        acc2 = __builtin_amdgcn_mfma_f32_16x16x32_bf16(af, b2, acc2, 0, 0, 0);
        acc3 = __builtin_amdgcn_mfma_f32_16x16x32_bf16(af, b3, acc3, 0, 0, 0);
    }
    // C/D layout: col = cb*16 + (lane&15), row = tile*16 + (lane>>4)*4 + r
    int c0 = lane & 15;
    long rbase = (long)(tile * 16 + (lane >> 4) * 4) * HD;
    #pragma unroll
    for (int r = 0; r < 4; r++) {
        hb[rbase + r * HD + c0]      = f2bf(acc0[r]);
        hb[rbase + r * HD + 16 + c0] = f2bf(acc1[r]);
        hb[rbase + r * HD + 32 + c0] = f2bf(acc2[r]);
        hb[rbase + r * HD + 48 + c0] = f2bf(acc3[r]);
    }
    // fused attention terms
    float wsv[4], wdv[4];
    #pragma unroll
    for (int cb = 0; cb < 4; cb++) {
        wsv[cb] = asrc_w[cb * 16 + c0];
        wdv[cb] = adst_w[cb * 16 + c0];
    }
    int nbase = tile * 16 + (lane >> 4) * 4;
    #pragma unroll
    for (int r = 0; r < 4; r++) {
        float a[4] = {acc0[r], acc1[r], acc2[r], acc3[r]};
        #pragma unroll
        for (int cb = 0; cb < 4; cb++) {
            float vs = a[cb] * wsv[cb];
            float vd = a[cb] * wdv[cb];
            vs += __shfl_xor(vs, 1, 64); vd += __shfl_xor(vd, 1, 64);
            vs += __shfl_xor(vs, 2, 64); vd += __shfl_xor(vd, 2, 64);
            vs += __shfl_xor(vs, 4, 64); vd += __shfl_xor(vd, 4, 64);
            if ((c0 & 7) == 0) {
                int hh = 2 * cb + (c0 >> 3);
                a_src[(nbase + r) * 8 + hh] = vs;
                a_dst[(nbase + r) * 8 + hh] = vd;
            }
        }
    }
}

// ================= CSR scan =================
__global__ void scan_block_kernel(const unsigned* __restrict__ deg,
                                  unsigned* __restrict__ rowptr,
                                  unsigned* __restrict__ bsum) {
    __shared__ unsigned sm[256];
    int i = blockIdx.x * 256 + threadIdx.x;
    unsigned v = (i < N_NODES) ? deg[i] : 0u;
    sm[threadIdx.x] = v;
    __syncthreads();
    #pragma unroll
    for (int off = 1; off < 256; off <<= 1) {
        unsigned u = (threadIdx.x >= off) ? sm[threadIdx.x - off] : 0u;
        __syncthreads();
        sm[threadIdx.x] += u;
        __syncthreads();
    }
    if (i < N_NODES) rowptr[i] = sm[threadIdx.x] - v;   // exclusive
    if (threadIdx.x == 255) bsum[blockIdx.x] = sm[255];
}

// fused top-scan + add
__global__ void scan_addtop_kernel(unsigned* __restrict__ rowptr,
                                   const unsigned* __restrict__ bsum) {
    __shared__ unsigned sm[256];
    int tid = threadIdx.x;
    unsigned v = (tid < NB_SCAN) ? bsum[tid] : 0u;
    sm[tid] = v;
    __syncthreads();
    #pragma unroll
    for (int off = 1; off < 256; off <<= 1) {
        unsigned u = (tid >= off) ? sm[tid - off] : 0u;
        __syncthreads();
        sm[tid] += u;
        __syncthreads();
    }
    unsigned prefix = (blockIdx.x == 0) ? 0u : sm[blockIdx.x - 1];
    int i = blockIdx.x * 256 + tid;
    if (i < N_NODES) rowptr[i] += prefix;
    if (i == 0) rowptr[N_NODES] = ETOT;
}

// fill: atomic-free scatter using recorded slots
__global__ void fill_kernel(const int* __restrict__ ei, const unsigned* __restrict__ rowptr,
                            const int* __restrict__ epos, int* __restrict__ col) {
    int e = blockIdx.x * blockDim.x + threadIdx.x;
    if (e >= ETOT) return;
    int s, t; edge_sd(ei, e, s, t);
    col[rowptr[t] + epos[e]] = s;
}

// ---- layer-1 agg + fused layer-2 projection (+b1) + layer-2 attention terms ----
__global__ __launch_bounds__(256) void agg1_proj2_kernel(const unsigned* __restrict__ rowptr,
                                                         const int* __restrict__ col,
                                                         const float* __restrict__ a_src,
                                                         const float* __restrict__ a_dst,
                                                         const unsigned short* __restrict__ hb,
                                                         const float* __restrict__ b1,
                                                         const float* __restrict__ W2,
                                                         const float* __restrict__ asrc2_w,
                                                         const float* __restrict__ adst2_w,
                                                         float* __restrict__ h2p,
                                                         float* __restrict__ a_src2,
                                                         float* __restrict__ a_dst2) {
    int n = blockIdx.x * 4 + (threadIdx.x >> 6);
    if (n >= N_NODES) return;
    int k = threadIdx.x & 63;
    int hh = k >> 3;
    float ad = a_dst[n * 8 + hh];
    int r0 = rowptr[n], r1 = rowptr[n + 1];
    float acc = 0.f, z = 0.f;
    int e = r0;
    for (; e + 3 < r1; e += 4) {   // 4 gathers in flight
        int s0 = col[e], s1 = col[e + 1], s2 = col[e + 2], s3 = col[e + 3];
        float as0 = a_src[s0 * 8 + hh];
        float as1 = a_src[s1 * 8 + hh];
        float as2 = a_src[s2 * 8 + hh];
        float as3 = a_src[s3 * 8 + hh];
        unsigned short u0 = hb[(long)s0 * 64 + k];
        unsigned short u1 = hb[(long)s1 * 64 + k];
        unsigned short u2 = hb[(long)s2 * 64 + k];
        unsigned short u3 = hb[(long)s3 * 64 + k];
        float p0 = __expf(lrelu(as0 + ad));
        float p1 = __expf(lrelu(as1 + ad));
        float p2 = __expf(lrelu(as2 + ad));
        float p3 = __expf(lrelu(as3 + ad));
        z += (p0 + p1) + (p2 + p3);
        acc += p0 * bf2f(u0) + p1 * bf2f(u1) + p2 * bf2f(u2) + p3 * bf2f(u3);
    }
    for (; e < r1; ++e) {
        int s0 = col[e];
        float p0 = __expf(lrelu(a_src[s0 * 8 + hh] + ad));
        z += p0;
        acc += p0 * bf2f(hb[(long)s0 * 64 + k]);
    }
    // fused proj2: v = out1[n][k] + b1[k]; h2 = sum_k v * W2[k][:]
    float v = acc / (z + 1e-16f) + b1[k];
    float part[NC];
    #pragma unroll
    for (int c = 0; c < NC; c++) part[c] = v * W2[k * NC + c];
    #pragma unroll
    for (int off = 32; off >= 1; off >>= 1)
        #pragma unroll
        for (int c = 0; c < NC; c++) part[c] += __shfl_xor(part[c], off, 64);
    if (k == 0) {
        float as = 0.f, ad2 = 0.f;
        #pragma unroll
        for (int c = 0; c < NC; c++) {
            as  += part[c] * asrc2_w[c];
            ad2 += part[c] * adst2_w[c];
        }
        f32x4 h0;
        h0[0] = part[0]; h0[1] = part[1]; h0[2] = part[2]; h0[3] = part[3];
        *reinterpret_cast<f32x4*>(&h2p[n * 8]) = h0;
        h2p[n * 8 + 4] = part[4];
        h2p[n * 8 + 5] = 0.f; h2p[n * 8 + 6] = 0.f; h2p[n * 8 + 7] = 0.f;
        a_src2[n] = as;
        a_dst2[n] = ad2;
    }
}

// ---------- layer-2 fused softmax+agg+bias+log_softmax (thread per node) ----------
__global__ void agg2_kernel(const unsigned* __restrict__ rowptr, const int* __restrict__ col,
                            const float* __restrict__ a_src2, const float* __restrict__ a_dst2,
                            const float* __restrict__ h2p, const float* __restrict__ b2,
                            float* __restrict__ y) {
    int n = blockIdx.x * blockDim.x + threadIdx.x;
    if (n >= N_NODES) return;
    float ad = a_dst2[n];
    int r0 = rowptr[n], r1 = rowptr[n + 1];
    float acc[NC] = {};
    float z = 0.f;
    int e = r0;
    for (; e + 3 < r1; e += 4) {   // 4 gathers in flight
        int s0 = col[e], s1 = col[e + 1], s2 = col[e + 2], s3 = col[e + 3];
        float as0 = a_src2[s0], as1 = a_src2[s1], as2 = a_src2[s2], as3 = a_src2[s3];
        f32x4 v0 = *reinterpret_cast<const f32x4*>(&h2p[s0 * 8]);
        f32x4 v1 = *reinterpret_cast<const f32x4*>(&h2p[s1 * 8]);
        f32x4 v2 = *reinterpret_cast<const f32x4*>(&h2p[s2 * 8]);
        f32x4 v3 = *reinterpret_cast<const f32x4*>(&h2p[s3 * 8]);
        float w0 = h2p[s0 * 8 + 4], w1 = h2p[s1 * 8 + 4], w2 = h2p[s2 * 8 + 4], w3 = h2p[s3 * 8 + 4];
        float p0 = __expf(lrelu(as0 + ad));
        float p1 = __expf(lrelu(as1 + ad));
        float p2 = __expf(lrelu(as2 + ad));
        float p3 = __expf(lrelu(as3 + ad));
        z += (p0 + p1) + (p2 + p3);
        #pragma unroll
        for (int c = 0; c < 4; c++)
            acc[c] += p0 * v0[c] + p1 * v1[c] + p2 * v2[c] + p3 * v3[c];
        acc[4] += p0 * w0 + p1 * w1 + p2 * w2 + p3 * w3;
    }
    for (; e < r1; ++e) {
        int s = col[e];
        float p = __expf(lrelu(a_src2[s] + ad));
        z += p;
        f32x4 v0 = *reinterpret_cast<const f32x4*>(&h2p[s * 8]);
        float v4 = h2p[s * 8 + 4];
        acc[0] += p * v0[0]; acc[1] += p * v0[1]; acc[2] += p * v0[2];
        acc[3] += p * v0[3]; acc[4] += p * v4;
    }
    float inv = 1.f / (z + 1e-16f);
    float l[NC], mx = -3.4e38f;
    #pragma unroll
    for (int c = 0; c < NC; c++) {
        l[c] = acc[c] * inv + b2[c];
        mx = fmaxf(mx, l[c]);
    }
    float ssum = 0.f;
    #pragma unroll
    for (int c = 0; c < NC; c++) ssum += __expf(l[c] - mx);
    float lse = __logf(ssum);
    #pragma unroll
    for (int c = 0; c < NC; c++) y[n * NC + c] = l[c] - mx - lse;
}

extern "C" void kernel_launch(void* const* d_in, const int* in_sizes, int n_in,
                              void* d_out, int out_size, void* d_ws, size_t ws_size,
                              hipStream_t stream) {
    const float* x        = (const float*)d_in[0];
    const int*   ei       = (const int*)d_in[1];
    const float* W1       = (const float*)d_in[2];
    const float* att_src1 = (const float*)d_in[3];
    const float* att_dst1 = (const float*)d_in[4];
    const float* b1       = (const float*)d_in[5];
    const float* W2       = (const float*)d_in[6];
    const float* att_src2 = (const float*)d_in[7];
    const float* att_dst2 = (const float*)d_in[8];
    const float* b2       = (const float*)d_in[9];
    float* y = (float*)d_out;

    // workspace layout
    unsigned short* hb = (unsigned short*)d_ws;           // N*64 bf16
    float* a_src1  = (float*)(hb + (long)N_NODES * 64);   // N*8
    float* a_dst1  = a_src1 + N_NODES * 8;                // N*8
    float* h2p     = a_dst1 + N_NODES * 8;                // N*8 (padded NC)
    float* a_src2  = h2p + (long)N_NODES * 8;             // N
    float* a_dst2  = a_src2 + N_NODES;                    // N
    unsigned* deg    = (unsigned*)(a_dst2 + N_NODES);     // N
    unsigned* rowptr = deg + N_NODES;                     // N+1
    unsigned* bsum   = rowptr + N_NODES + 1;              // 256
    int*      col    = (int*)(bsum + 256);                // ETOT
    int*      epos   = col + ETOT;                        // ETOT
    short*    Wp     = (short*)(epos + ETOT);             // 147456 shorts

    hipMemsetAsync(deg, 0, N_NODES * sizeof(unsigned), stream);
    packW_kernel<<<(KB * 4 * 64 + 255) / 256, 256, 0, stream>>>(W1, Wp);

    // gemm1 (+fused att1) || hist, one fat launch
    fat_gemm_hist<<<GEMM_BLOCKS + HIST_BLOCKS, 256, 0, stream>>>(
        x, Wp, att_src1, att_dst1, hb, a_src1, a_dst1, ei, deg, epos);

    scan_block_kernel<<<NB_SCAN, 256, 0, stream>>>(deg, rowptr, bsum);
    scan_addtop_kernel<<<NB_SCAN, 256, 0, stream>>>(rowptr, bsum);
    fill_kernel<<<(ETOT + 255) / 256, 256, 0, stream>>>(ei, rowptr, epos, col);

    agg1_proj2_kernel<<<(N_NODES + 3) / 4, 256, 0, stream>>>(rowptr, col, a_src1, a_dst1, hb,
                                                             b1, W2, att_src2, att_dst2,
                                                             h2p, a_src2, a_dst2);
    agg2_kernel<<<(N_NODES + 255) / 256, 256, 0, stream>>>(rowptr, col, a_src2, a_dst2, h2p, b2, y);
}